// Round 1
// baseline (7802.598 us; speedup 1.0000x reference)
//
#include <hip/hip_runtime.h>

#define THREADS 256
#define NUM_STEPS 5

__global__ void init_kernel(const float* __restrict__ prior,
                            float* __restrict__ p,
                            float* __restrict__ prod,
                            float* __restrict__ agg, int n) {
    int i = blockIdx.x * blockDim.x + threadIdx.x;
    if (i < n) {
        p[i] = prior[i];
        prod[i] = 1.0f;
        agg[i] = 0.0f;
    }
}

// Each thread processes 4 edges: vectorized 16B loads of src/dst/prob,
// gather p[src] (2MB table, L2-resident), atomic scatter into agg[dst].
__global__ void edge_kernel(const int* __restrict__ src,
                            const int* __restrict__ dst,
                            const float* __restrict__ ep,
                            const float* __restrict__ p,
                            float* __restrict__ agg,
                            int e4, int e_rem, long long e4base) {
    int i = blockIdx.x * blockDim.x + threadIdx.x;
    if (i < e4) {
        int4   s = ((const int4*)src)[i];
        int4   t = ((const int4*)dst)[i];
        float4 w = ((const float4*)ep)[i];
        atomicAdd(&agg[t.x], w.x * p[s.x]);
        atomicAdd(&agg[t.y], w.y * p[s.y]);
        atomicAdd(&agg[t.z], w.z * p[s.z]);
        atomicAdd(&agg[t.w], w.w * p[s.w]);
    }
    // scalar tail (E % 4), handled by first few threads of block 0
    if (blockIdx.x == 0 && threadIdx.x < e_rem) {
        long long e = e4base + threadIdx.x;
        atomicAdd(&agg[dst[e]], ep[e] * p[src[e]]);
    }
}

__global__ void node_kernel(float* __restrict__ p,
                            float* __restrict__ prod,
                            float* __restrict__ agg,
                            const float* __restrict__ prior,
                            float* __restrict__ out,
                            int n, int final_step) {
    int i = blockIdx.x * blockDim.x + threadIdx.x;
    if (i < n) {
        float a = agg[i];
        agg[i] = 0.0f;                    // reset for next step (no memset needed)
        float delta = 1.0f - expf(-a);
        float pr_old = prod[i];
        float np_ = pr_old * delta;
        float pr = pr_old * (1.0f - np_);
        prod[i] = pr;
        p[i] = np_;
        if (final_step) out[i] = 1.0f - pr + prior[i];
    }
}

extern "C" void kernel_launch(void* const* d_in, const int* in_sizes, int n_in,
                              void* d_out, int out_size, void* d_ws, size_t ws_size,
                              hipStream_t stream) {
    const float* prior = (const float*)d_in[0];
    const int*   eidx  = (const int*)d_in[1];
    const float* ep    = (const float*)d_in[2];

    const int n = in_sizes[0];
    const long long E = (long long)in_sizes[2];
    const int* src = eidx;          // edge_index[0, :]
    const int* dst = eidx + E;      // edge_index[1, :]

    float* p    = (float*)d_ws;
    float* prod = p + n;
    float* agg  = prod + n;
    float* out  = (float*)d_out;

    const int nb_n = (n + THREADS - 1) / THREADS;
    init_kernel<<<nb_n, THREADS, 0, stream>>>(prior, p, prod, agg, n);

    const int e4 = (int)(E / 4);
    const int e_rem = (int)(E % 4);
    const long long e4base = (long long)e4 * 4;
    const int nb_e = (e4 + THREADS - 1) / THREADS;

    for (int step = 0; step < NUM_STEPS; ++step) {
        edge_kernel<<<nb_e, THREADS, 0, stream>>>(src, dst, ep, p, agg, e4, e_rem, e4base);
        node_kernel<<<nb_n, THREADS, 0, stream>>>(p, prod, agg, prior, out, n,
                                                  step == NUM_STEPS - 1 ? 1 : 0);
    }
}

// Round 2
// 2337.731 us; speedup vs baseline: 3.3377x; 3.3377x over previous
//
#include <hip/hip_runtime.h>

#define NUM_STEPS 5
typedef unsigned int u32;

// ---------------- fast path constants ----------------
#define RSH 8              // 256 nodes per bucket
#define RSZ 256
#define SB  512            // histogram/scatter blocks
#define ST  512            // histogram/scatter threads
#define SRC_BITS 19        // N=500000 < 2^19
#define SRC_MASK 0x7FFFFu

static inline size_t align256(size_t x){ return (x + 255) & ~(size_t)255; }

// ---------------- fast-path kernels ----------------

__global__ void init_fast(const float* __restrict__ prior, float* __restrict__ p0,
                          float* __restrict__ prod, int n){
    int i = blockIdx.x*blockDim.x + threadIdx.x;
    if(i<n){ p0[i]=prior[i]; prod[i]=1.0f; }
}

// per-block histogram of edge targets into B buckets
__global__ void hist_kernel(const int* __restrict__ dst, long long E, int B,
                            u32* __restrict__ blk_cnt){
    extern __shared__ u32 hist[];
    int sb = blockIdx.x;
    long long chunk = (E + SB - 1)/SB;
    long long e0 = (long long)sb*chunk;
    long long e1 = e0 + chunk; if(e1 > E) e1 = E;
    for(int b=threadIdx.x; b<B; b+=blockDim.x) hist[b]=0;
    __syncthreads();
    for(long long e=e0+threadIdx.x; e<e1; e+=blockDim.x){
        int b = ((u32)dst[e]) >> RSH;
        atomicAdd(&hist[b], 1u);
    }
    __syncthreads();
    for(int b=threadIdx.x; b<B; b+=blockDim.x) blk_cnt[(size_t)sb*B + b] = hist[b];
}

// per-bucket exclusive scan over the SB per-block counts (one block per bucket);
// overwrites blk_cnt in place with exclusive prefixes, writes bucket totals.
__global__ void colscan_kernel(u32* __restrict__ blk_cnt, int B, u32* __restrict__ tot){
    __shared__ u32 s[256];
    int b = blockIdx.x, t = threadIdx.x;
    u32 v0 = blk_cnt[(size_t)(2*t  )*B + b];
    u32 v1 = blk_cnt[(size_t)(2*t+1)*B + b];
    u32 sum = v0 + v1;
    s[t] = sum; __syncthreads();
    for(int off=1; off<256; off<<=1){
        u32 x = (t>=off) ? s[t-off] : 0;
        __syncthreads();
        s[t] += x;
        __syncthreads();
    }
    u32 excl = s[t] - sum;
    blk_cnt[(size_t)(2*t  )*B + b] = excl;
    blk_cnt[(size_t)(2*t+1)*B + b] = excl + v0;
    if(t==255) tot[b] = s[255];
}

// exclusive scan of bucket totals -> bucket base offsets (single block)
__global__ void basescan_kernel(const u32* __restrict__ tot, u32* __restrict__ base, int B){
    __shared__ u32 s[256];
    int t = threadIdx.x;
    u32 v[8]; u32 sum = 0;
    #pragma unroll
    for(int k=0;k<8;k++){ int b=t*8+k; v[k] = (b<B)? tot[b] : 0; sum += v[k]; }
    s[t] = sum; __syncthreads();
    for(int off=1; off<256; off<<=1){
        u32 x = (t>=off) ? s[t-off] : 0;
        __syncthreads();
        s[t] += x;
        __syncthreads();
    }
    u32 run = s[t] - sum;  // exclusive prefix of this thread's chunk
    #pragma unroll
    for(int k=0;k<8;k++){ int b=t*8+k; if(b<B) base[b]=run; run += v[k]; }
    if(t==255) base[B] = run;   // == E
}

// scatter edges into bucket-sorted arrays
__global__ void scatter_kernel(const int* __restrict__ src, const int* __restrict__ dst,
                               const float* __restrict__ ep, long long E, int B,
                               const u32* __restrict__ blk_rel, const u32* __restrict__ base,
                               u32* __restrict__ packed, float* __restrict__ eps){
    extern __shared__ u32 cur[];
    int sb = blockIdx.x;
    long long chunk = (E + SB - 1)/SB;
    long long e0 = (long long)sb*chunk;
    long long e1 = e0 + chunk; if(e1 > E) e1 = E;
    for(int b=threadIdx.x; b<B; b+=blockDim.x)
        cur[b] = base[b] + blk_rel[(size_t)sb*B + b];
    __syncthreads();
    for(long long e=e0+threadIdx.x; e<e1; e+=blockDim.x){
        u32 d = (u32)dst[e];
        int b = d >> RSH;
        u32 pos = atomicAdd(&cur[b], 1u);
        packed[pos] = ((u32)src[e]) | ((d & (RSZ-1)) << SRC_BITS);
        eps[pos]    = ep[e];
    }
}

// one step: each block owns one bucket (256 nodes); LDS accumulation, fused node update
__global__ void step_kernel(const u32* __restrict__ packed, const float* __restrict__ eps,
                            const u32* __restrict__ base,
                            const float* __restrict__ p_cur, float* __restrict__ p_nxt,
                            float* __restrict__ prod, const float* __restrict__ prior,
                            float* __restrict__ out, int n, int final_step){
    __shared__ float acc[RSZ];
    int b = blockIdx.x;
    acc[threadIdx.x] = 0.0f;          // blockDim.x == RSZ
    __syncthreads();
    u32 e0 = base[b], e1 = base[b+1];
    for(u32 e = e0 + threadIdx.x; e < e1; e += blockDim.x){
        u32 pk = packed[e];
        float m = eps[e] * p_cur[pk & SRC_MASK];
        atomicAdd(&acc[pk >> SRC_BITS], m);
    }
    __syncthreads();
    int i = (b << RSH) + threadIdx.x;
    if(i < n){
        float a = acc[threadIdx.x];
        float pr_old = prod[i];
        float np = pr_old * (1.0f - expf(-a));
        float pr = pr_old * (1.0f - np);
        prod[i]  = pr;
        p_nxt[i] = np;
        if(final_step) out[i] = 1.0f - pr + prior[i];
    }
}

// ---------------- fallback (round-1) kernels ----------------

__global__ void init_kernel(const float* __restrict__ prior, float* __restrict__ p,
                            float* __restrict__ prod, float* __restrict__ agg, int n){
    int i = blockIdx.x*blockDim.x + threadIdx.x;
    if(i<n){ p[i]=prior[i]; prod[i]=1.0f; agg[i]=0.0f; }
}

__global__ void edge_kernel(const int* __restrict__ src, const int* __restrict__ dst,
                            const float* __restrict__ ep, const float* __restrict__ p,
                            float* __restrict__ agg, int e4, int e_rem, long long e4base){
    int i = blockIdx.x*blockDim.x + threadIdx.x;
    if(i < e4){
        int4   s = ((const int4*)src)[i];
        int4   t = ((const int4*)dst)[i];
        float4 w = ((const float4*)ep)[i];
        atomicAdd(&agg[t.x], w.x * p[s.x]);
        atomicAdd(&agg[t.y], w.y * p[s.y]);
        atomicAdd(&agg[t.z], w.z * p[s.z]);
        atomicAdd(&agg[t.w], w.w * p[s.w]);
    }
    if(blockIdx.x==0 && threadIdx.x < e_rem){
        long long e = e4base + threadIdx.x;
        atomicAdd(&agg[dst[e]], ep[e]*p[src[e]]);
    }
}

__global__ void node_kernel(float* __restrict__ p, float* __restrict__ prod,
                            float* __restrict__ agg, const float* __restrict__ prior,
                            float* __restrict__ out, int n, int final_step){
    int i = blockIdx.x*blockDim.x + threadIdx.x;
    if(i<n){
        float a = agg[i]; agg[i]=0.0f;
        float pr_old = prod[i];
        float np = pr_old*(1.0f - expf(-a));
        float pr = pr_old*(1.0f - np);
        prod[i]=pr; p[i]=np;
        if(final_step) out[i] = 1.0f - pr + prior[i];
    }
}

// ---------------- launch ----------------

extern "C" void kernel_launch(void* const* d_in, const int* in_sizes, int n_in,
                              void* d_out, int out_size, void* d_ws, size_t ws_size,
                              hipStream_t stream){
    const float* prior = (const float*)d_in[0];
    const int*   eidx  = (const int*)d_in[1];
    const float* ep    = (const float*)d_in[2];

    const int n = in_sizes[0];
    const long long E = (long long)in_sizes[2];
    const int* src = eidx;
    const int* dst = eidx + E;
    float* out = (float*)d_out;

    const int B = (n + RSZ - 1) >> RSH;   // buckets

    // ws layout for fast path
    size_t szN   = align256((size_t)n * 4);
    size_t szB1  = align256((size_t)(B + 1) * 4);
    size_t szB   = align256((size_t)B * 4);
    size_t szCnt = align256((size_t)SB * B * 4);
    size_t szE   = align256((size_t)E * 4);

    size_t off_p0   = 0;
    size_t off_p1   = off_p0 + szN;
    size_t off_prod = off_p1 + szN;
    size_t off_base = off_prod + szN;
    size_t off_tot  = off_base + szB1;
    size_t off_cnt  = off_tot + szB;
    size_t off_pk   = off_cnt + szCnt;
    size_t off_ep   = off_pk + szE;
    size_t need     = off_ep + szE;

    char* ws = (char*)d_ws;

    if(ws_size >= need && n < (1 << SRC_BITS)){
        float* p0   = (float*)(ws + off_p0);
        float* p1   = (float*)(ws + off_p1);
        float* prod = (float*)(ws + off_prod);
        u32*   base = (u32*)  (ws + off_base);
        u32*   tot  = (u32*)  (ws + off_tot);
        u32*   cnt  = (u32*)  (ws + off_cnt);
        u32*   pk   = (u32*)  (ws + off_pk);
        float* eps  = (float*)(ws + off_ep);

        const int nb_n = (n + 255)/256;
        init_fast<<<nb_n, 256, 0, stream>>>(prior, p0, prod, n);
        hist_kernel<<<SB, ST, (size_t)B*4, stream>>>(dst, E, B, cnt);
        colscan_kernel<<<B, 256, 0, stream>>>(cnt, B, tot);
        basescan_kernel<<<1, 256, 0, stream>>>(tot, base, B);
        scatter_kernel<<<SB, ST, (size_t)B*4, stream>>>(src, dst, ep, E, B, cnt, base, pk, eps);

        float* pc = p0;
        float* pn = p1;
        for(int step=0; step<NUM_STEPS; ++step){
            step_kernel<<<B, RSZ, 0, stream>>>(pk, eps, base, pc, pn, prod, prior, out,
                                               n, step == NUM_STEPS-1 ? 1 : 0);
            float* t2 = pc; pc = pn; pn = t2;
        }
    } else {
        // fallback: global-atomic version (round 1)
        float* p    = (float*)d_ws;
        float* prod = p + n;
        float* agg  = prod + n;
        const int nb_n = (n + 255)/256;
        init_kernel<<<nb_n, 256, 0, stream>>>(prior, p, prod, agg, n);
        const int e4 = (int)(E/4);
        const int e_rem = (int)(E%4);
        const long long e4base = (long long)e4*4;
        const int nb_e = (e4 + 255)/256;
        for(int step=0; step<NUM_STEPS; ++step){
            edge_kernel<<<nb_e, 256, 0, stream>>>(src, dst, ep, p, agg, e4, e_rem, e4base);
            node_kernel<<<nb_n, 256, 0, stream>>>(p, prod, agg, prior, out, n,
                                                  step == NUM_STEPS-1 ? 1 : 0);
        }
    }
}

// Round 3
// 1338.662 us; speedup vs baseline: 5.8287x; 1.7463x over previous
//
#include <hip/hip_runtime.h>

#define NUM_STEPS 5
typedef unsigned int u32;

// ---------------- fast path constants ----------------
#define RSH 10             // 1024 nodes per bucket
#define RSZ 1024
#define SB  256            // histogram/scatter blocks (matched between hist & scatter!)
#define ST  512            // histogram/scatter threads
#define SRC_BITS 19        // N=500000 < 2^19
#define SRC_MASK 0x7FFFFu

static inline size_t align256(size_t x){ return (x + 255) & ~(size_t)255; }

// ---------------- fast-path kernels ----------------

__global__ void init_fast(const float* __restrict__ prior, float* __restrict__ p0,
                          float* __restrict__ prod, int n){
    int i = blockIdx.x*blockDim.x + threadIdx.x;
    if(i<n){ p0[i]=prior[i]; prod[i]=1.0f; }
}

// per-block histogram of edge targets into B buckets (int4-vectorized)
__global__ void hist_kernel(const int* __restrict__ dst, long long E, int B,
                            u32* __restrict__ blk_cnt){
    extern __shared__ u32 hist[];
    int sb = blockIdx.x;
    long long E4 = E >> 2;
    long long chunk = (E4 + SB - 1)/SB;
    long long i0 = (long long)sb*chunk;
    long long i1 = i0 + chunk; if(i1 > E4) i1 = E4;
    for(int b=threadIdx.x; b<B; b+=blockDim.x) hist[b]=0;
    __syncthreads();
    const int4* d4 = (const int4*)dst;
    for(long long i=i0+threadIdx.x; i<i1; i+=blockDim.x){
        int4 d = d4[i];
        atomicAdd(&hist[((u32)d.x)>>RSH], 1u);
        atomicAdd(&hist[((u32)d.y)>>RSH], 1u);
        atomicAdd(&hist[((u32)d.z)>>RSH], 1u);
        atomicAdd(&hist[((u32)d.w)>>RSH], 1u);
    }
    if(sb==0){   // scalar tail (E % 4)
        for(long long e=(E4<<2)+threadIdx.x; e<E; e+=blockDim.x)
            atomicAdd(&hist[((u32)dst[e])>>RSH], 1u);
    }
    __syncthreads();
    for(int b=threadIdx.x; b<B; b+=blockDim.x) blk_cnt[(size_t)sb*B + b] = hist[b];
}

// per-bucket exclusive scan over the SB per-block counts (one block per bucket)
__global__ void colscan_kernel(u32* __restrict__ blk_cnt, int B, u32* __restrict__ tot){
    __shared__ u32 s[SB];
    int b = blockIdx.x, t = threadIdx.x;   // blockDim.x == SB
    u32 v = blk_cnt[(size_t)t*B + b];
    s[t] = v; __syncthreads();
    for(int off=1; off<SB; off<<=1){
        u32 x = (t>=off) ? s[t-off] : 0;
        __syncthreads();
        s[t] += x;
        __syncthreads();
    }
    blk_cnt[(size_t)t*B + b] = s[t] - v;     // exclusive
    if(t==SB-1) tot[b] = s[SB-1];
}

// exclusive scan of bucket totals -> bucket base offsets (single block, B <= 512)
__global__ void basescan_kernel(const u32* __restrict__ tot, u32* __restrict__ base, int B){
    __shared__ u32 s[256];
    int t = threadIdx.x;
    u32 v0 = (2*t   < B) ? tot[2*t]   : 0;
    u32 v1 = (2*t+1 < B) ? tot[2*t+1] : 0;
    u32 sum = v0 + v1;
    s[t] = sum; __syncthreads();
    for(int off=1; off<256; off<<=1){
        u32 x = (t>=off) ? s[t-off] : 0;
        __syncthreads();
        s[t] += x;
        __syncthreads();
    }
    u32 run = s[t] - sum;
    if(2*t   < B) base[2*t]   = run;
    if(2*t+1 < B) base[2*t+1] = run + v0;
    if(t==255) base[B] = s[255];     // == E
}

// scatter edges into bucket-sorted single uint2 array {src|dst_local<<19, prob_bits}
__global__ void scatter_kernel(const int* __restrict__ src, const int* __restrict__ dst,
                               const float* __restrict__ ep, long long E, int B,
                               const u32* __restrict__ blk_rel, const u32* __restrict__ base,
                               uint2* __restrict__ edges){
    extern __shared__ u32 cur[];
    int sb = blockIdx.x;
    long long E4 = E >> 2;
    long long chunk = (E4 + SB - 1)/SB;
    long long i0 = (long long)sb*chunk;
    long long i1 = i0 + chunk; if(i1 > E4) i1 = E4;
    for(int b=threadIdx.x; b<B; b+=blockDim.x)
        cur[b] = base[b] + blk_rel[(size_t)sb*B + b];
    __syncthreads();
    const int4*   s4 = (const int4*)src;
    const int4*   d4 = (const int4*)dst;
    const float4* w4 = (const float4*)ep;
    for(long long i=i0+threadIdx.x; i<i1; i+=blockDim.x){
        int4 s = s4[i]; int4 d = d4[i]; float4 w = w4[i];
        u32 dd, pos;
        dd=(u32)d.x; pos=atomicAdd(&cur[dd>>RSH],1u);
        edges[pos]=make_uint2(((u32)s.x)|((dd&(RSZ-1))<<SRC_BITS), __float_as_uint(w.x));
        dd=(u32)d.y; pos=atomicAdd(&cur[dd>>RSH],1u);
        edges[pos]=make_uint2(((u32)s.y)|((dd&(RSZ-1))<<SRC_BITS), __float_as_uint(w.y));
        dd=(u32)d.z; pos=atomicAdd(&cur[dd>>RSH],1u);
        edges[pos]=make_uint2(((u32)s.z)|((dd&(RSZ-1))<<SRC_BITS), __float_as_uint(w.z));
        dd=(u32)d.w; pos=atomicAdd(&cur[dd>>RSH],1u);
        edges[pos]=make_uint2(((u32)s.w)|((dd&(RSZ-1))<<SRC_BITS), __float_as_uint(w.w));
    }
    if(sb==0){   // scalar tail (E % 4)
        for(long long e=(E4<<2)+threadIdx.x; e<E; e+=blockDim.x){
            u32 dd=(u32)dst[e];
            u32 pos=atomicAdd(&cur[dd>>RSH],1u);
            edges[pos]=make_uint2(((u32)src[e])|((dd&(RSZ-1))<<SRC_BITS), __float_as_uint(ep[e]));
        }
    }
}

// one step: each block owns one 1024-node bucket; 2-replica LDS accumulation,
// fused node update (delta/prod/p, plus final output write on last step)
__global__ __launch_bounds__(512) void
step_kernel(const uint2* __restrict__ edges, const u32* __restrict__ base,
            const float* __restrict__ p_cur, float* __restrict__ p_nxt,
            float* __restrict__ prod, const float* __restrict__ prior,
            float* __restrict__ out, int n, int final_step){
    __shared__ float acc[2][RSZ];
    int b = blockIdx.x, t = threadIdx.x;
    for(int k=t; k<RSZ; k+=blockDim.x){ acc[0][k]=0.0f; acc[1][k]=0.0f; }
    __syncthreads();
    u32 e0 = base[b], e1 = base[b+1];
    int rep = t & 1;
    for(u32 e = e0 + t; e < e1; e += blockDim.x){
        uint2 pk = edges[e];
        float m = __uint_as_float(pk.y) * p_cur[pk.x & SRC_MASK];
        atomicAdd(&acc[rep][pk.x >> SRC_BITS], m);
    }
    __syncthreads();
    int i0 = b << RSH;
    for(int k=t; k<RSZ; k+=blockDim.x){
        int i = i0 + k;
        if(i < n){
            float a = acc[0][k] + acc[1][k];
            float pr_old = prod[i];
            float np = pr_old * (1.0f - expf(-a));
            float pr = pr_old * (1.0f - np);
            prod[i]  = pr;
            p_nxt[i] = np;
            if(final_step) out[i] = 1.0f - pr + prior[i];
        }
    }
}

// ---------------- fallback (round-1) kernels ----------------

__global__ void init_kernel(const float* __restrict__ prior, float* __restrict__ p,
                            float* __restrict__ prod, float* __restrict__ agg, int n){
    int i = blockIdx.x*blockDim.x + threadIdx.x;
    if(i<n){ p[i]=prior[i]; prod[i]=1.0f; agg[i]=0.0f; }
}

__global__ void edge_kernel(const int* __restrict__ src, const int* __restrict__ dst,
                            const float* __restrict__ ep, const float* __restrict__ p,
                            float* __restrict__ agg, int e4, int e_rem, long long e4base){
    int i = blockIdx.x*blockDim.x + threadIdx.x;
    if(i < e4){
        int4   s = ((const int4*)src)[i];
        int4   t = ((const int4*)dst)[i];
        float4 w = ((const float4*)ep)[i];
        atomicAdd(&agg[t.x], w.x * p[s.x]);
        atomicAdd(&agg[t.y], w.y * p[s.y]);
        atomicAdd(&agg[t.z], w.z * p[s.z]);
        atomicAdd(&agg[t.w], w.w * p[s.w]);
    }
    if(blockIdx.x==0 && threadIdx.x < e_rem){
        long long e = e4base + threadIdx.x;
        atomicAdd(&agg[dst[e]], ep[e]*p[src[e]]);
    }
}

__global__ void node_kernel(float* __restrict__ p, float* __restrict__ prod,
                            float* __restrict__ agg, const float* __restrict__ prior,
                            float* __restrict__ out, int n, int final_step){
    int i = blockIdx.x*blockDim.x + threadIdx.x;
    if(i<n){
        float a = agg[i]; agg[i]=0.0f;
        float pr_old = prod[i];
        float np = pr_old*(1.0f - expf(-a));
        float pr = pr_old*(1.0f - np);
        prod[i]=pr; p[i]=np;
        if(final_step) out[i] = 1.0f - pr + prior[i];
    }
}

// ---------------- launch ----------------

extern "C" void kernel_launch(void* const* d_in, const int* in_sizes, int n_in,
                              void* d_out, int out_size, void* d_ws, size_t ws_size,
                              hipStream_t stream){
    const float* prior = (const float*)d_in[0];
    const int*   eidx  = (const int*)d_in[1];
    const float* ep    = (const float*)d_in[2];

    const int n = in_sizes[0];
    const long long E = (long long)in_sizes[2];
    const int* src = eidx;
    const int* dst = eidx + E;
    float* out = (float*)d_out;

    const int B = (n + RSZ - 1) >> RSH;   // buckets (489 for n=500000)

    // ws layout for fast path
    size_t szN   = align256((size_t)n * 4);
    size_t szB1  = align256((size_t)(B + 1) * 4);
    size_t szB   = align256((size_t)B * 4);
    size_t szCnt = align256((size_t)SB * B * 4);
    size_t szE2  = align256((size_t)E * 8);

    size_t off_p0   = 0;
    size_t off_p1   = off_p0 + szN;
    size_t off_prod = off_p1 + szN;
    size_t off_base = off_prod + szN;
    size_t off_tot  = off_base + szB1;
    size_t off_cnt  = off_tot + szB;
    size_t off_edge = off_cnt + szCnt;
    size_t need     = off_edge + szE2;

    char* ws = (char*)d_ws;

    if(ws_size >= need && n < (1 << SRC_BITS) && B <= 512){
        float* p0    = (float*)(ws + off_p0);
        float* p1    = (float*)(ws + off_p1);
        float* prod  = (float*)(ws + off_prod);
        u32*   base  = (u32*)  (ws + off_base);
        u32*   tot   = (u32*)  (ws + off_tot);
        u32*   cnt   = (u32*)  (ws + off_cnt);
        uint2* edges = (uint2*)(ws + off_edge);

        const int nb_n = (n + 255)/256;
        init_fast<<<nb_n, 256, 0, stream>>>(prior, p0, prod, n);
        hist_kernel<<<SB, ST, (size_t)B*4, stream>>>(dst, E, B, cnt);
        colscan_kernel<<<B, SB, 0, stream>>>(cnt, B, tot);
        basescan_kernel<<<1, 256, 0, stream>>>(tot, base, B);
        scatter_kernel<<<SB, ST, (size_t)B*4, stream>>>(src, dst, ep, E, B, cnt, base, edges);

        float* pc = p0;
        float* pn = p1;
        for(int step=0; step<NUM_STEPS; ++step){
            step_kernel<<<B, 512, 0, stream>>>(edges, base, pc, pn, prod, prior, out,
                                               n, step == NUM_STEPS-1 ? 1 : 0);
            float* t2 = pc; pc = pn; pn = t2;
        }
    } else {
        // fallback: global-atomic version (round 1)
        float* p    = (float*)d_ws;
        float* prod = p + n;
        float* agg  = prod + n;
        const int nb_n = (n + 255)/256;
        init_kernel<<<nb_n, 256, 0, stream>>>(prior, p, prod, agg, n);
        const int e4 = (int)(E/4);
        const int e_rem = (int)(E%4);
        const long long e4base = (long long)e4*4;
        const int nb_e = (e4 + 255)/256;
        for(int step=0; step<NUM_STEPS; ++step){
            edge_kernel<<<nb_e, 256, 0, stream>>>(src, dst, ep, p, agg, e4, e_rem, e4base);
            node_kernel<<<nb_n, 256, 0, stream>>>(p, prod, agg, prior, out, n,
                                                  step == NUM_STEPS-1 ? 1 : 0);
        }
    }
}